// Round 10
// baseline (298.933 us; speedup 1.0000x reference)
//
#include <hip/hip_runtime.h>

// ---------------------------------------------------------------------------
// SparseMultiHeadAttention (windowed, W=4) forward on MI355X / gfx950
// R10: QKV GEMM ported to the 256x256 8-wave counted-vmcnt phase schedule
//      (T2 swizzle + T3/T4 counted vmcnt + raw s_barrier + T5 setprio).
//      gemm_out stays at the proven 128x128 structure; attn_k owns the
//      1.07GB weights write (serial arrangement, proven R7/R9).
// ---------------------------------------------------------------------------

typedef __attribute__((ext_vector_type(8))) short short8;
typedef __attribute__((ext_vector_type(4))) float f32x4;

#define B_    4
#define S_    2048
#define D_    1024
#define H_    16
#define HD_   64
#define WIN_  4
#define NROW  (B_ * S_)                           /* 8192 */
#define OUT0_ELEMS  ((size_t)B_ * S_ * D_)        /* 8388608 */

__device__ __forceinline__ unsigned short f2bf(float f) {
  unsigned int u = __float_as_uint(f);
  u += 0x7fffu + ((u >> 16) & 1u);                // round-to-nearest-even
  return (unsigned short)(u >> 16);
}
__device__ __forceinline__ float bf2f(unsigned short u) {
  return __uint_as_float(((unsigned int)u) << 16);
}

// ---------------- fp32 -> bf16 elementwise (x) ------------------------------
__global__ __launch_bounds__(256) void xconv_k(const float* __restrict__ x,
                                               unsigned short* __restrict__ o) {
  int i = blockIdx.x * 256 + threadIdx.x;         // one float4 per thread
  float4 f = reinterpret_cast<const float4*>(x)[i];
  ushort4 u;
  u.x = f2bf(f.x); u.y = f2bf(f.y); u.z = f2bf(f.z); u.w = f2bf(f.w);
  reinterpret_cast<ushort4*>(o)[i] = u;
}

// ---------------- fp32 [K][N] -> bf16 transposed [N][K] (4 weight mats) -----
__global__ __launch_bounds__(256) void wconv_k(const float* __restrict__ W0,
                                               const float* __restrict__ W1,
                                               const float* __restrict__ W2,
                                               const float* __restrict__ W3,
                                               unsigned short* __restrict__ out) {
  __shared__ float t[32][33];
  const float* Ws[4] = {W0, W1, W2, W3};
  const float* W = Ws[blockIdx.z];
  unsigned short* o = out + (size_t)blockIdx.z * D_ * D_;
  int tx = threadIdx.x;                           // 0..31
  int ty = threadIdx.y;                           // 0..7
  int n0 = blockIdx.x * 32, k0 = blockIdx.y * 32;
#pragma unroll
  for (int i = 0; i < 4; ++i)
    t[ty + 8 * i][tx] = W[(size_t)(k0 + ty + 8 * i) * D_ + (n0 + tx)];
  __syncthreads();
#pragma unroll
  for (int i = 0; i < 4; ++i)
    o[(size_t)(n0 + ty + 8 * i) * D_ + (k0 + tx)] = f2bf(t[tx][ty + 8 * i]);
}

#define GLD16(g, l)                                                            \
  __builtin_amdgcn_global_load_lds(                                            \
      (const __attribute__((address_space(1))) unsigned int*)(g),              \
      (__attribute__((address_space(3))) unsigned int*)(l), 16, 0, 0)

#define MFMA16(a, b, c) __builtin_amdgcn_mfma_f32_16x16x32_bf16(a, b, c, 0, 0, 0)

// ---------------- fused QKV GEMM (M=8192, N=3072, K=1024), bf16 out --------
// 384 blocks x 512 thr. 256x256 tile, BK=64, 8 waves (2M x 4N, 128x64/wave).
// Double-buffered 128KB LDS; per iteration: stage next K-tile (8 gload_lds),
// counted vmcnt(8) (next tile floats), raw barrier, 4 phases of
// {ds_read subtile -> barrier -> setprio(1) -> 16 MFMA -> setprio(0) -> barrier}.
__global__ __launch_bounds__(512, 2) void gemm_qkv_k(
    const unsigned short* __restrict__ A, const unsigned short* __restrict__ Wt,
    const float* __restrict__ bq, const float* __restrict__ bk,
    const float* __restrict__ bv, unsigned short* __restrict__ Qb,
    unsigned short* __restrict__ Kb, unsigned short* __restrict__ Vb) {
  __shared__ unsigned short As[2][256 * 64];      // 64 KB
  __shared__ unsigned short Bs[2][256 * 64];      // 64 KB

  const int bid = blockIdx.x;                     // 384
  const int xcd = bid & 7, chunk = bid >> 3;      // bijective: 384 % 8 == 0
  const int gt = xcd * 48 + chunk;                // XCD owns 4 consecutive mt
  const int row0 = (gt / 12) * 256;
  const int col0 = (gt % 12) * 256;

  const int tid = threadIdx.x;
  const int lane = tid & 63;
  const int wid = tid >> 6;                       // 0..7
  const int wm = wid >> 2, wn = wid & 3;          // 2M x 4N waves
  const int frow = lane & 15;
  const int cpb = lane >> 4;                      // 0..3

  // lane-dependent swizzled byte bases into a [256][64] bf16 tile (128B rows)
  const int abase = (wm * 128 + frow) * 128 + ((cpb ^ (frow & 7)) << 4);
  const int bbase = (wn * 64 + frow) * 128 + ((cpb ^ (frow & 7)) << 4);

  f32x4 acc[8][4] = {};

  // stage K-tile kt into buffer bb: 4 rounds x (A,B), source pre-swizzled
#define STAGE_QKV(kt, bb)                                                      \
  {                                                                            \
    _Pragma("unroll") for (int i = 0; i < 4; ++i) {                            \
      int c = tid + (i << 9);          /* 0..2047 */                           \
      int r = c >> 3;                  /* 0..255 */                            \
      int jj = (c & 7) ^ (r & 7);      /* inverse swizzle on source */         \
      GLD16(A + (size_t)(row0 + r) * D_ + ((kt) << 6) + (jj << 3),             \
            (char*)&As[bb][0] + c * 16);                                       \
      GLD16(Wt + (size_t)(col0 + r) * D_ + ((kt) << 6) + (jj << 3),            \
            (char*)&Bs[bb][0] + c * 16);                                       \
    }                                                                          \
  }

  STAGE_QKV(0, 0);                                // prologue

  for (int kt = 0; kt < 16; ++kt) {
    const int cur = kt & 1;
    if (kt < 15) {
      STAGE_QKV(kt + 1, cur ^ 1);
      asm volatile("s_waitcnt vmcnt(8)" ::: "memory");   // counted: next floats
    } else {
      asm volatile("s_waitcnt vmcnt(0)" ::: "memory");
    }
    __builtin_amdgcn_s_barrier();
    __builtin_amdgcn_sched_barrier(0);

    const char* Ac = (const char*)&As[cur][0];
    const char* Bc = (const char*)&Bs[cur][0];
    short8 a0[8], bfr[2];

    // ---- phase 0: A[0..7]@ks0 + B[0,1]@ks0 ; MFMA mi x {0,1}
#pragma unroll
    for (int mi = 0; mi < 8; ++mi)
      a0[mi] = *reinterpret_cast<const short8*>(Ac + (abase + mi * 2048));
    bfr[0] = *reinterpret_cast<const short8*>(Bc + (bbase + 0 * 2048));
    bfr[1] = *reinterpret_cast<const short8*>(Bc + (bbase + 1 * 2048));
    __builtin_amdgcn_sched_barrier(0);
    __builtin_amdgcn_s_barrier();
    __builtin_amdgcn_s_setprio(1);
#pragma unroll
    for (int mi = 0; mi < 8; ++mi) {
      acc[mi][0] = MFMA16(a0[mi], bfr[0], acc[mi][0]);
      acc[mi][1] = MFMA16(a0[mi], bfr[1], acc[mi][1]);
    }
    __builtin_amdgcn_s_setprio(0);
    __builtin_amdgcn_sched_barrier(0);
    __builtin_amdgcn_s_barrier();

    // ---- phase 1: B[2,3]@ks0 ; MFMA mi x {2,3}
    bfr[0] = *reinterpret_cast<const short8*>(Bc + (bbase + 2 * 2048));
    bfr[1] = *reinterpret_cast<const short8*>(Bc + (bbase + 3 * 2048));
    __builtin_amdgcn_sched_barrier(0);
    __builtin_amdgcn_s_barrier();
    __builtin_amdgcn_s_setprio(1);
#pragma unroll
    for (int mi = 0; mi < 8; ++mi) {
      acc[mi][2] = MFMA16(a0[mi], bfr[0], acc[mi][2]);
      acc[mi][3] = MFMA16(a0[mi], bfr[1], acc[mi][3]);
    }
    __builtin_amdgcn_s_setprio(0);
    __builtin_amdgcn_sched_barrier(0);
    __builtin_amdgcn_s_barrier();

    // ---- phase 2: A[0..7]@ks1 + B[0,1]@ks1 ; MFMA mi x {0,1}
#pragma unroll
    for (int mi = 0; mi < 8; ++mi)
      a0[mi] = *reinterpret_cast<const short8*>(Ac + ((abase ^ 64) + mi * 2048));
    bfr[0] = *reinterpret_cast<const short8*>(Bc + ((bbase ^ 64) + 0 * 2048));
    bfr[1] = *reinterpret_cast<const short8*>(Bc + ((bbase ^ 64) + 1 * 2048));
    __builtin_amdgcn_sched_barrier(0);
    __builtin_amdgcn_s_barrier();
    __builtin_amdgcn_s_setprio(1);
#pragma unroll
    for (int mi = 0; mi < 8; ++mi) {
      acc[mi][0] = MFMA16(a0[mi], bfr[0], acc[mi][0]);
      acc[mi][1] = MFMA16(a0[mi], bfr[1], acc[mi][1]);
    }
    __builtin_amdgcn_s_setprio(0);
    __builtin_amdgcn_sched_barrier(0);
    __builtin_amdgcn_s_barrier();

    // ---- phase 3: B[2,3]@ks1 ; MFMA mi x {2,3}
    bfr[0] = *reinterpret_cast<const short8*>(Bc + ((bbase ^ 64) + 2 * 2048));
    bfr[1] = *reinterpret_cast<const short8*>(Bc + ((bbase ^ 64) + 3 * 2048));
    __builtin_amdgcn_sched_barrier(0);
    __builtin_amdgcn_s_barrier();
    __builtin_amdgcn_s_setprio(1);
#pragma unroll
    for (int mi = 0; mi < 8; ++mi) {
      acc[mi][2] = MFMA16(a0[mi], bfr[0], acc[mi][2]);
      acc[mi][3] = MFMA16(a0[mi], bfr[1], acc[mi][3]);
    }
    __builtin_amdgcn_s_setprio(0);
    __builtin_amdgcn_sched_barrier(0);
    __builtin_amdgcn_s_barrier();                 // guards buf overwrite
  }

  // ---- epilogue: bias + per-head bf16 scatter (m89-verified C/D layout)
  const int z = col0 >> 10;                       // block-uniform
  const float* bias = (z == 0) ? bq : (z == 1) ? bk : bv;
  unsigned short* outp = (z == 0) ? Qb : (z == 1) ? Kb : Vb;
  const int cbase = col0 & 1023;
#pragma unroll
  for (int mi = 0; mi < 8; ++mi) {
#pragma unroll
    for (int ni = 0; ni < 4; ++ni) {
#pragma unroll
      for (int r = 0; r < 4; ++r) {
        int gr = row0 + wm * 128 + mi * 16 + ((lane >> 4) << 2) + r;
        int ci = cbase + wn * 64 + ni * 16 + (lane & 15);
        int bb = gr >> 11, s = gr & (S_ - 1);
        int h = ci >> 6, hd = ci & 63;
        outp[(((size_t)(bb * H_ + h) * S_ + s) << 6) + hd] =
            f2bf(acc[mi][ni][r] + bias[ci]);
      }
    }
  }
}

// ---------------- out GEMM (M=8192, N=1024, K=1024), fp32 out --------------
// 512 blocks, XCD map; BK=64 swizzled (proven R9 structure).
__global__ __launch_bounds__(256) void gemm_out_k(
    const unsigned short* __restrict__ A, const unsigned short* __restrict__ Bt,
    const float* __restrict__ bias, float* __restrict__ o_) {
  __shared__ unsigned short As[128 * 64];
  __shared__ unsigned short Bs[128 * 64];
  const int g = blockIdx.x;
  const int o = g & 7, gg = g >> 3;               // gg in 0..63
  const int row0 = (o * 8 + (gg & 7)) * 128;
  const int col0 = (gg >> 3) * 128;

  const int tid = threadIdx.x;
  const int lane = tid & 63;
  const int wid = tid >> 6;
  const int wm = wid >> 1, wn = wid & 1;

  f32x4 acc[4][4] = {};
  const int frow = lane & 15;
  const int cpb = lane >> 4;

  for (int kt = 0; kt < 16; ++kt) {
#pragma unroll
    for (int i = 0; i < 4; ++i) {
      int c = tid + (i << 8);
      int r = c >> 3;
      int jj = (c & 7) ^ (r & 7);
      GLD16(A + (size_t)(row0 + r) * D_ + (kt << 6) + (jj << 3),
            (char*)As + c * 16);
      GLD16(Bt + (size_t)(col0 + r) * D_ + (kt << 6) + (jj << 3),
            (char*)Bs + c * 16);
    }
    __syncthreads();
#pragma unroll
    for (int ks = 0; ks < 2; ++ks) {
      short8 af[4], bfr[4];
#pragma unroll
      for (int mi = 0; mi < 4; ++mi) {
        int row = wm * 64 + mi * 16 + frow;
        int swz = (ks * 4 + cpb) ^ (row & 7);
        af[mi] = *reinterpret_cast<const short8*>((char*)As + row * 128 + swz * 16);
      }
#pragma unroll
      for (int ni = 0; ni < 4; ++ni) {
        int row = wn * 64 + ni * 16 + frow;
        int swz = (ks * 4 + cpb) ^ (row & 7);
        bfr[ni] = *reinterpret_cast<const short8*>((char*)Bs + row * 128 + swz * 16);
      }
#pragma unroll
      for (int mi = 0; mi < 4; ++mi)
#pragma unroll
        for (int ni = 0; ni < 4; ++ni)
          acc[mi][ni] = MFMA16(af[mi], bfr[ni], acc[mi][ni]);
    }
    __syncthreads();
  }

#pragma unroll
  for (int mi = 0; mi < 4; ++mi) {
#pragma unroll
    for (int ni = 0; ni < 4; ++ni) {
#pragma unroll
      for (int r = 0; r < 4; ++r) {
        int gr = row0 + wm * 64 + mi * 16 + ((lane >> 4) << 2) + r;
        int gc = col0 + wn * 64 + ni * 16 + (lane & 15);
        o_[(size_t)gr * D_ + gc] = acc[mi][ni][r] + bias[gc];
      }
    }
  }
}

// ---------------- banded attention + full weights-row write ----------------
__global__ __launch_bounds__(256) void attn_k(const unsigned short* __restrict__ Q,
                                              const unsigned short* __restrict__ K,
                                              const unsigned short* __restrict__ V,
                                              float* __restrict__ wout,
                                              unsigned short* __restrict__ attn) {
  int lane = threadIdx.x & 63;
  int wid = threadIdx.x >> 6;
  int row = blockIdx.x * 4 + wid;       // bh*2048 + s
  int s = row & (S_ - 1);
  int bh = row >> 11;                   // b*16 + h
  int b = bh >> 4, h = bh & 15;
  float qd = bf2f(Q[(size_t)row * HD_ + lane]);
  const unsigned short* Kb = K + (size_t)bh * S_ * HD_;
  const unsigned short* Vb = V + (size_t)bh * S_ * HD_;

  float sc[9];
#pragma unroll
  for (int j = 0; j < 9; ++j) {
    int ks = s - WIN_ + j;
    bool ok = (ks >= 0) && (ks < S_);
    float v = ok ? qd * bf2f(Kb[(size_t)ks * HD_ + lane]) : 0.f;
#pragma unroll
    for (int off = 32; off > 0; off >>= 1) v += __shfl_xor(v, off, 64);
    sc[j] = ok ? v * 0.125f : -INFINITY;  // 1/sqrt(64)
  }
  float m = sc[0];
#pragma unroll
  for (int j = 1; j < 9; ++j) m = fmaxf(m, sc[j]);
  float w[9];
  float sum = 0.f;
#pragma unroll
  for (int j = 0; j < 9; ++j) { w[j] = __expf(sc[j] - m); sum += w[j]; }
  float inv = 1.f / sum;
#pragma unroll
  for (int j = 0; j < 9; ++j) w[j] *= inv;  // wave-uniform normalized weights

  float o = 0.f;
#pragma unroll
  for (int j = 0; j < 9; ++j) {
    int ks = s - WIN_ + j;
    if (ks >= 0 && ks < S_) o += w[j] * bf2f(Vb[(size_t)ks * HD_ + lane]);
  }
  attn[((size_t)(b * S_ + s)) * D_ + h * HD_ + lane] = f2bf(o);

  // ---- full weights row: 8 NT f32x4 per lane, band select-merged ----
  f32x4* rowp = reinterpret_cast<f32x4*>(wout + (size_t)row * S_);
  const int lo = s - WIN_;              // first band col (may be <0)
  const int hi = s + WIN_;              // last band col (may be >=S_)
#pragma unroll
  for (int i = 0; i < 8; ++i) {
    int f = lane + (i << 6);            // f32x4 chunk 0..511
    int c0 = f << 2;                    // first col of chunk
    f32x4 v4 = {0.f, 0.f, 0.f, 0.f};
    if (c0 + 3 >= lo && c0 <= hi) {     // chunk overlaps band (<=3 lanes)
#pragma unroll
      for (int e = 0; e < 4; ++e) {
        int d = c0 + e - lo;            // band index if in [0,8]
        float val = 0.f;
#pragma unroll
        for (int j = 0; j < 9; ++j)
          if (d == j) val = w[j];       // static-index select chain
        v4[e] = val;
      }
    }
    __builtin_nontemporal_store(v4, rowp + f);
  }
}

// ---------------------------------------------------------------------------
extern "C" void kernel_launch(void* const* d_in, const int* in_sizes, int n_in,
                              void* d_out, int out_size, void* d_ws,
                              size_t ws_size, hipStream_t stream) {
  const float* x = (const float*)d_in[0];
  const float* Wq = (const float*)d_in[1];
  const float* bq = (const float*)d_in[2];
  const float* Wk = (const float*)d_in[3];
  const float* bk = (const float*)d_in[4];
  const float* Wv = (const float*)d_in[5];
  const float* bv = (const float*)d_in[6];
  const float* Wo = (const float*)d_in[7];
  const float* bo = (const float*)d_in[8];
  float* out = (float*)d_out;
  float* wout = out + OUT0_ELEMS;

  char* ws = (char*)d_ws;
  unsigned short* x_bf = (unsigned short*)(ws);                  // 16 MB @ 0
  unsigned short* Wt = (unsigned short*)(ws + (16ull << 20));    //  8 MB @ 16
  unsigned short* Qb = (unsigned short*)(ws + (24ull << 20));    // 16 MB @ 24
  unsigned short* Kb = (unsigned short*)(ws + (40ull << 20));    // 16 MB @ 40
  unsigned short* Vb = (unsigned short*)(ws + (56ull << 20));    // 16 MB @ 56
  unsigned short* attn = (unsigned short*)(ws + (72ull << 20));  // 16 MB @ 72

  xconv_k<<<NROW * D_ / 1024, 256, 0, stream>>>(x, x_bf);
  wconv_k<<<dim3(32, 32, 4), dim3(32, 8), 0, stream>>>(Wq, Wk, Wv, Wo, Wt);
  gemm_qkv_k<<<384, 512, 0, stream>>>(x_bf, Wt, bq, bk, bv, Qb, Kb, Vb);
  attn_k<<<(B_ * H_ * S_) / 4, 256, 0, stream>>>(Qb, Kb, Vb, wout, attn);
  gemm_out_k<<<512, 256, 0, stream>>>(attn, Wt + (size_t)3 * D_ * D_, bo, out);
}

// Round 11
// 296.226 us; speedup vs baseline: 1.0091x; 1.0091x over previous
//
#include <hip/hip_runtime.h>

// ---------------------------------------------------------------------------
// SparseMultiHeadAttention (windowed, W=4) forward on MI355X / gfx950
// R11: R7 structure (best measured: serial arrangement, BK=32 m97 GEMMs,
//      attn_k owns the 1.07GB weights write). Cleanups: row-major QKV
//      buffers (linear GEMM epilogue), NT store on final out.
//   x -> bf16                                  (xconv_k)
//   Wq/Wk/Wv/Wo -> bf16 transposed [N][K]      (wconv_k)
//   QKV = x@[Wq|Wk|Wv]+b, bf16 row-major       (gemm_qkv_k, 1536 blk)
//   banded softmax + PV + FULL weights-row     (attn_k, owns 1.07GB write)
//   out = attn@Wo + bo, fp32 NT                (gemm_out_k, 512 blk)
// ---------------------------------------------------------------------------

typedef __attribute__((ext_vector_type(8))) short short8;
typedef __attribute__((ext_vector_type(4))) float f32x4;

#define B_    4
#define S_    2048
#define D_    1024
#define H_    16
#define HD_   64
#define WIN_  4
#define NROW  (B_ * S_)                           /* 8192 */
#define OUT0_ELEMS  ((size_t)B_ * S_ * D_)        /* 8388608 */

__device__ __forceinline__ unsigned short f2bf(float f) {
  unsigned int u = __float_as_uint(f);
  u += 0x7fffu + ((u >> 16) & 1u);                // round-to-nearest-even
  return (unsigned short)(u >> 16);
}
__device__ __forceinline__ float bf2f(unsigned short u) {
  return __uint_as_float(((unsigned int)u) << 16);
}

// ---------------- fp32 -> bf16 elementwise (x) ------------------------------
__global__ __launch_bounds__(256) void xconv_k(const float* __restrict__ x,
                                               unsigned short* __restrict__ o) {
  int i = blockIdx.x * 256 + threadIdx.x;         // one float4 per thread
  float4 f = reinterpret_cast<const float4*>(x)[i];
  ushort4 u;
  u.x = f2bf(f.x); u.y = f2bf(f.y); u.z = f2bf(f.z); u.w = f2bf(f.w);
  reinterpret_cast<ushort4*>(o)[i] = u;
}

// ---------------- fp32 [K][N] -> bf16 transposed [N][K] (4 weight mats) -----
__global__ __launch_bounds__(256) void wconv_k(const float* __restrict__ W0,
                                               const float* __restrict__ W1,
                                               const float* __restrict__ W2,
                                               const float* __restrict__ W3,
                                               unsigned short* __restrict__ out) {
  __shared__ float t[32][33];
  const float* Ws[4] = {W0, W1, W2, W3};
  const float* W = Ws[blockIdx.z];
  unsigned short* o = out + (size_t)blockIdx.z * D_ * D_;
  int tx = threadIdx.x;                           // 0..31
  int ty = threadIdx.y;                           // 0..7
  int n0 = blockIdx.x * 32, k0 = blockIdx.y * 32;
#pragma unroll
  for (int i = 0; i < 4; ++i)
    t[ty + 8 * i][tx] = W[(size_t)(k0 + ty + 8 * i) * D_ + (n0 + tx)];
  __syncthreads();
#pragma unroll
  for (int i = 0; i < 4; ++i)
    o[(size_t)(n0 + ty + 8 * i) * D_ + (k0 + tx)] = f2bf(t[tx][ty + 8 * i]);
}

#define GLD16(g, l)                                                            \
  __builtin_amdgcn_global_load_lds(                                            \
      (const __attribute__((address_space(1))) unsigned int*)(g),              \
      (__attribute__((address_space(3))) unsigned int*)(l), 16, 0, 0)

#define MFMA16(a, b, c) __builtin_amdgcn_mfma_f32_16x16x32_bf16(a, b, c, 0, 0, 0)

// ---------------- fused QKV GEMM (M=8192, N=3072, K=1024), bf16 out --------
// 1536 blocks, XCD map: o=b&7 (XCD), gg=b>>3; row0=(o*8+gg%8)*128 (A panel
// pinned per XCD L2), col0=(gg/8)*128. Row-major [8192][1024] outputs.
__global__ __launch_bounds__(256) void gemm_qkv_k(
    const unsigned short* __restrict__ A, const unsigned short* __restrict__ Wt,
    const float* __restrict__ bq, const float* __restrict__ bk,
    const float* __restrict__ bv, unsigned short* __restrict__ Qb,
    unsigned short* __restrict__ Kb, unsigned short* __restrict__ Vb) {
  __shared__ unsigned short As[128 * 32];
  __shared__ unsigned short Bs[128 * 32];
  const int g = blockIdx.x;
  const int o = g & 7, gg = g >> 3;               // gg in 0..191
  const int row0 = (o * 8 + (gg & 7)) * 128;
  const int col0 = (gg >> 3) * 128;               // 24 col tiles (N=3072)

  const int tid = threadIdx.x;
  const int lane = tid & 63;
  const int wid = tid >> 6;
  const int wm = wid >> 1, wn = wid & 1;

  f32x4 acc[4][4] = {};
  const int frow = lane & 15;
  const int koff = (lane >> 4) << 3;

  for (int kt = 0; kt < 32; ++kt) {
#pragma unroll
    for (int i = 0; i < 2; ++i) {
      int c = tid + (i << 8);
      int r = c >> 2;
      int kk = (c & 3) << 3;
      GLD16(A + (size_t)(row0 + r) * D_ + (kt << 5) + kk, (char*)As + c * 16);
      GLD16(Wt + (size_t)(col0 + r) * D_ + (kt << 5) + kk, (char*)Bs + c * 16);
    }
    __syncthreads();
    short8 af[4], bfr[4];
#pragma unroll
    for (int mi = 0; mi < 4; ++mi)
      af[mi] = *reinterpret_cast<const short8*>(
          &As[(wm * 64 + mi * 16 + frow) * 32 + koff]);
#pragma unroll
    for (int ni = 0; ni < 4; ++ni)
      bfr[ni] = *reinterpret_cast<const short8*>(
          &Bs[(wn * 64 + ni * 16 + frow) * 32 + koff]);
#pragma unroll
    for (int mi = 0; mi < 4; ++mi)
#pragma unroll
      for (int ni = 0; ni < 4; ++ni)
        acc[mi][ni] = MFMA16(af[mi], bfr[ni], acc[mi][ni]);
    __syncthreads();
  }

  const int z = col0 >> 10;                       // block-uniform
  const float* bias = (z == 0) ? bq : (z == 1) ? bk : bv;
  unsigned short* outp = (z == 0) ? Qb : (z == 1) ? Kb : Vb;
  const int cb = col0 & 1023;
#pragma unroll
  for (int mi = 0; mi < 4; ++mi) {
#pragma unroll
    for (int ni = 0; ni < 4; ++ni) {
#pragma unroll
      for (int r = 0; r < 4; ++r) {
        int gr = row0 + wm * 64 + mi * 16 + ((lane >> 4) << 2) + r;
        int ci = cb + wn * 64 + ni * 16 + (lane & 15);
        outp[(size_t)gr * D_ + ci] = f2bf(acc[mi][ni][r] + bias[ci]);
      }
    }
  }
}

// ---------------- out GEMM (M=8192, N=1024, K=1024), fp32 NT out -----------
// 512 blocks, same XCD map (64 row x 8 col tiles).
__global__ __launch_bounds__(256) void gemm_out_k(
    const unsigned short* __restrict__ A, const unsigned short* __restrict__ Bt,
    const float* __restrict__ bias, float* __restrict__ o_) {
  __shared__ unsigned short As[128 * 32];
  __shared__ unsigned short Bs[128 * 32];
  const int g = blockIdx.x;
  const int o = g & 7, gg = g >> 3;               // gg in 0..63
  const int row0 = (o * 8 + (gg & 7)) * 128;
  const int col0 = (gg >> 3) * 128;

  const int tid = threadIdx.x;
  const int lane = tid & 63;
  const int wid = tid >> 6;
  const int wm = wid >> 1, wn = wid & 1;

  f32x4 acc[4][4] = {};
  const int frow = lane & 15;
  const int koff = (lane >> 4) << 3;

  for (int kt = 0; kt < 32; ++kt) {
#pragma unroll
    for (int i = 0; i < 2; ++i) {
      int c = tid + (i << 8);
      int r = c >> 2;
      int kk = (c & 3) << 3;
      GLD16(A + (size_t)(row0 + r) * D_ + (kt << 5) + kk, (char*)As + c * 16);
      GLD16(Bt + (size_t)(col0 + r) * D_ + (kt << 5) + kk, (char*)Bs + c * 16);
    }
    __syncthreads();
    short8 af[4], bfr[4];
#pragma unroll
    for (int mi = 0; mi < 4; ++mi)
      af[mi] = *reinterpret_cast<const short8*>(
          &As[(wm * 64 + mi * 16 + frow) * 32 + koff]);
#pragma unroll
    for (int ni = 0; ni < 4; ++ni)
      bfr[ni] = *reinterpret_cast<const short8*>(
          &Bs[(wn * 64 + ni * 16 + frow) * 32 + koff]);
#pragma unroll
    for (int mi = 0; mi < 4; ++mi)
#pragma unroll
      for (int ni = 0; ni < 4; ++ni)
        acc[mi][ni] = MFMA16(af[mi], bfr[ni], acc[mi][ni]);
    __syncthreads();
  }

#pragma unroll
  for (int mi = 0; mi < 4; ++mi) {
#pragma unroll
    for (int ni = 0; ni < 4; ++ni) {
#pragma unroll
      for (int r = 0; r < 4; ++r) {
        int gr = row0 + wm * 64 + mi * 16 + ((lane >> 4) << 2) + r;
        int gc = col0 + wn * 64 + ni * 16 + (lane & 15);
        __builtin_nontemporal_store(acc[mi][ni][r] + bias[gc],
                                    &o_[(size_t)gr * D_ + gc]);
      }
    }
  }
}

// ---------------- banded attention + full weights-row write ----------------
// one wave per (b,h,q) row; Q/K/V row-major [B*S][D]. 64 lanes write the
// entire 2048-float weights row (zeros + 9 band values) as NT f32x4.
__global__ __launch_bounds__(256) void attn_k(const unsigned short* __restrict__ Q,
                                              const unsigned short* __restrict__ K,
                                              const unsigned short* __restrict__ V,
                                              float* __restrict__ wout,
                                              unsigned short* __restrict__ attn) {
  int lane = threadIdx.x & 63;
  int wid = threadIdx.x >> 6;
  int row = blockIdx.x * 4 + wid;       // bh*2048 + s (weights row id)
  int s = row & (S_ - 1);
  int bh = row >> 11;                   // b*16 + h
  int b = bh >> 4, h = bh & 15;
  const size_t rbase = (size_t)(b * S_) * D_ + h * HD_ + lane;  // row-major
  float qd = bf2f(Q[rbase + (size_t)s * D_]);

  float sc[9];
#pragma unroll
  for (int j = 0; j < 9; ++j) {
    int ks = s - WIN_ + j;
    bool ok = (ks >= 0) && (ks < S_);
    float v = ok ? qd * bf2f(K[rbase + (size_t)ks * D_]) : 0.f;
#pragma unroll
    for (int off = 32; off > 0; off >>= 1) v += __shfl_xor(v, off, 64);
    sc[j] = ok ? v * 0.125f : -INFINITY;  // 1/sqrt(64)
  }
  float m = sc[0];
#pragma unroll
  for (int j = 1; j < 9; ++j) m = fmaxf(m, sc[j]);
  float w[9];
  float sum = 0.f;
#pragma unroll
  for (int j = 0; j < 9; ++j) { w[j] = __expf(sc[j] - m); sum += w[j]; }
  float inv = 1.f / sum;
#pragma unroll
  for (int j = 0; j < 9; ++j) w[j] *= inv;  // wave-uniform normalized weights

  float o = 0.f;
#pragma unroll
  for (int j = 0; j < 9; ++j) {
    int ks = s - WIN_ + j;
    if (ks >= 0 && ks < S_) o += w[j] * bf2f(V[rbase + (size_t)ks * D_]);
  }
  attn[(size_t)(b * S_ + s) * D_ + h * HD_ + lane] = f2bf(o);

  // ---- full weights row: 8 NT f32x4 per lane, band select-merged ----
  f32x4* rowp = reinterpret_cast<f32x4*>(wout + (size_t)row * S_);
  const int lo = s - WIN_;              // first band col (may be <0)
  const int hi = s + WIN_;              // last band col (may be >=S_)
#pragma unroll
  for (int i = 0; i < 8; ++i) {
    int f = lane + (i << 6);            // f32x4 chunk 0..511
    int c0 = f << 2;                    // first col of chunk
    f32x4 v4 = {0.f, 0.f, 0.f, 0.f};
    if (c0 + 3 >= lo && c0 <= hi) {     // chunk overlaps band (<=3 lanes)
#pragma unroll
      for (int e = 0; e < 4; ++e) {
        int d = c0 + e - lo;            // band index if in [0,8]
        float val = 0.f;
#pragma unroll
        for (int j = 0; j < 9; ++j)
          if (d == j) val = w[j];       // static-index select chain
        v4[e] = val;
      }
    }
    __builtin_nontemporal_store(v4, rowp + f);
  }
}

// ---------------------------------------------------------------------------
extern "C" void kernel_launch(void* const* d_in, const int* in_sizes, int n_in,
                              void* d_out, int out_size, void* d_ws,
                              size_t ws_size, hipStream_t stream) {
  const float* x = (const float*)d_in[0];
  const float* Wq = (const float*)d_in[1];
  const float* bq = (const float*)d_in[2];
  const float* Wk = (const float*)d_in[3];
  const float* bk = (const float*)d_in[4];
  const float* Wv = (const float*)d_in[5];
  const float* bv = (const float*)d_in[6];
  const float* Wo = (const float*)d_in[7];
  const float* bo = (const float*)d_in[8];
  float* out = (float*)d_out;
  float* wout = out + OUT0_ELEMS;

  char* ws = (char*)d_ws;
  unsigned short* x_bf = (unsigned short*)(ws);                  // 16 MB @ 0
  unsigned short* Wt = (unsigned short*)(ws + (16ull << 20));    //  8 MB @ 16
  unsigned short* Qb = (unsigned short*)(ws + (24ull << 20));    // 16 MB @ 24
  unsigned short* Kb = (unsigned short*)(ws + (40ull << 20));    // 16 MB @ 40
  unsigned short* Vb = (unsigned short*)(ws + (56ull << 20));    // 16 MB @ 56
  unsigned short* attn = (unsigned short*)(ws + (72ull << 20));  // 16 MB @ 72

  xconv_k<<<NROW * D_ / 1024, 256, 0, stream>>>(x, x_bf);
  wconv_k<<<dim3(32, 32, 4), dim3(32, 8), 0, stream>>>(Wq, Wk, Wv, Wo, Wt);
  gemm_qkv_k<<<1536, 256, 0, stream>>>(x_bf, Wt, bq, bk, bv, Qb, Kb, Vb);
  attn_k<<<(B_ * H_ * S_) / 4, 256, 0, stream>>>(Qb, Kb, Vb, wout, attn);
  gemm_out_k<<<512, 256, 0, stream>>>(attn, Wt + (size_t)3 * D_ * D_, bo, out);
}

// Round 12
// 280.583 us; speedup vs baseline: 1.0654x; 1.0558x over previous
//
#include <hip/hip_runtime.h>

// ---------------------------------------------------------------------------
// SparseMultiHeadAttention (windowed, W=4) forward on MI355X / gfx950
// R12: exact R7 structure (best measured 282.6us) + merged prep dispatch.
//   x -> bf16  AND  Wq/Wk/Wv/Wo -> bf16 [N][K]  (prep_k, one dispatch)
//   QKV = x@[Wq|Wk|Wv]+b, bf16 per-head layout  (gemm_qkv_k, 1536 blk)
//   banded softmax + PV + FULL weights-row       (attn_k, owns 1.07GB write)
//   out = attn@Wo + bo, fp32                     (gemm_out_k, 512 blk)
// Measured dead-ends (do not revisit): fill inside GEMM K-loop (R5/R8) and
// filler-block specialization (R6) — NT fill starves staging / drains
// vmcnt(0) barriers; 8-phase 256^2 port without fine interleave (R10);
// row-major QKV + scalar NT out stores (R11).
// ---------------------------------------------------------------------------

typedef __attribute__((ext_vector_type(8))) short short8;
typedef __attribute__((ext_vector_type(4))) float f32x4;

#define B_    4
#define S_    2048
#define D_    1024
#define H_    16
#define HD_   64
#define WIN_  4
#define NROW  (B_ * S_)                           /* 8192 */
#define OUT0_ELEMS  ((size_t)B_ * S_ * D_)        /* 8388608 */

__device__ __forceinline__ unsigned short f2bf(float f) {
  unsigned int u = __float_as_uint(f);
  u += 0x7fffu + ((u >> 16) & 1u);                // round-to-nearest-even
  return (unsigned short)(u >> 16);
}
__device__ __forceinline__ float bf2f(unsigned short u) {
  return __uint_as_float(((unsigned int)u) << 16);
}

// ---------------- prep: x->bf16 (blocks 0..8191) ; W^T->bf16 (8192..12287) --
__global__ __launch_bounds__(256) void prep_k(const float* __restrict__ x,
                                              const float* __restrict__ W0,
                                              const float* __restrict__ W1,
                                              const float* __restrict__ W2,
                                              const float* __restrict__ W3,
                                              unsigned short* __restrict__ xo,
                                              unsigned short* __restrict__ Wt) {
  __shared__ float t[32][33];
  const int b = blockIdx.x;
  if (b < 8192) {                                 // ---- xconv: 1 float4/thr
    int i = b * 256 + threadIdx.x;
    float4 f = reinterpret_cast<const float4*>(x)[i];
    ushort4 u;
    u.x = f2bf(f.x); u.y = f2bf(f.y); u.z = f2bf(f.z); u.w = f2bf(f.w);
    reinterpret_cast<ushort4*>(xo)[i] = u;
    return;
  }
  const int wb = b - 8192;                        // ---- wconv: 32x32 tile
  const int z = wb >> 10;
  const int rem = wb & 1023;
  const int n0 = (rem & 31) * 32, k0 = (rem >> 5) * 32;
  const float* Ws[4] = {W0, W1, W2, W3};
  const float* W = Ws[z];
  unsigned short* o = Wt + (size_t)z * D_ * D_;
  const int tx = threadIdx.x & 31;                // 0..31
  const int ty = threadIdx.x >> 5;                // 0..7
#pragma unroll
  for (int i = 0; i < 4; ++i)
    t[ty + 8 * i][tx] = W[(size_t)(k0 + ty + 8 * i) * D_ + (n0 + tx)];
  __syncthreads();
#pragma unroll
  for (int i = 0; i < 4; ++i)
    o[(size_t)(n0 + ty + 8 * i) * D_ + (k0 + tx)] = f2bf(t[tx][ty + 8 * i]);
}

#define GLD16(g, l)                                                            \
  __builtin_amdgcn_global_load_lds(                                            \
      (const __attribute__((address_space(1))) unsigned int*)(g),              \
      (__attribute__((address_space(3))) unsigned int*)(l), 16, 0, 0)

#define MFMA16(a, b, c) __builtin_amdgcn_mfma_f32_16x16x32_bf16(a, b, c, 0, 0, 0)

// ---------------- fused QKV GEMM (M=8192, N=3072, K=1024), bf16 out --------
// 1536 blocks, XCD map: o=b&7 (XCD), gg=b>>3; row0=(o*8+gg%8)*128 (A panel
// pinned per XCD L2), col0=(gg/8)*128. Per-head [B,H,S,Hd] outputs.
__global__ __launch_bounds__(256) void gemm_qkv_k(
    const unsigned short* __restrict__ A, const unsigned short* __restrict__ Wt,
    const float* __restrict__ bq, const float* __restrict__ bk,
    const float* __restrict__ bv, unsigned short* __restrict__ Qb,
    unsigned short* __restrict__ Kb, unsigned short* __restrict__ Vb) {
  __shared__ unsigned short As[128 * 32];
  __shared__ unsigned short Bs[128 * 32];
  const int g = blockIdx.x;
  const int o = g & 7, gg = g >> 3;               // gg in 0..191
  const int row0 = (o * 8 + (gg & 7)) * 128;
  const int col0 = (gg >> 3) * 128;               // 24 col tiles (N=3072)

  const int tid = threadIdx.x;
  const int lane = tid & 63;
  const int wid = tid >> 6;
  const int wm = wid >> 1, wn = wid & 1;

  f32x4 acc[4][4] = {};
  const int frow = lane & 15;
  const int koff = (lane >> 4) << 3;

  for (int kt = 0; kt < 32; ++kt) {
#pragma unroll
    for (int i = 0; i < 2; ++i) {
      int c = tid + (i << 8);
      int r = c >> 2;
      int kk = (c & 3) << 3;
      GLD16(A + (size_t)(row0 + r) * D_ + (kt << 5) + kk, (char*)As + c * 16);
      GLD16(Wt + (size_t)(col0 + r) * D_ + (kt << 5) + kk, (char*)Bs + c * 16);
    }
    __syncthreads();
    short8 af[4], bfr[4];
#pragma unroll
    for (int mi = 0; mi < 4; ++mi)
      af[mi] = *reinterpret_cast<const short8*>(
          &As[(wm * 64 + mi * 16 + frow) * 32 + koff]);
#pragma unroll
    for (int ni = 0; ni < 4; ++ni)
      bfr[ni] = *reinterpret_cast<const short8*>(
          &Bs[(wn * 64 + ni * 16 + frow) * 32 + koff]);
#pragma unroll
    for (int mi = 0; mi < 4; ++mi)
#pragma unroll
      for (int ni = 0; ni < 4; ++ni)
        acc[mi][ni] = MFMA16(af[mi], bfr[ni], acc[mi][ni]);
    __syncthreads();
  }

#pragma unroll
  for (int mi = 0; mi < 4; ++mi) {
#pragma unroll
    for (int ni = 0; ni < 4; ++ni) {
#pragma unroll
      for (int r = 0; r < 4; ++r) {
        int gr = row0 + wm * 64 + mi * 16 + ((lane >> 4) << 2) + r;
        int gc = col0 + wn * 64 + ni * 16 + (lane & 15);
        int z = gc >> 10;                          // block-uniform
        int ci = gc & 1023;
        float bias = (z == 0) ? bq[ci] : (z == 1) ? bk[ci] : bv[ci];
        unsigned short* outp = (z == 0) ? Qb : (z == 1) ? Kb : Vb;
        int bb = gr >> 11, s = gr & (S_ - 1);
        int h = ci >> 6, hd = ci & 63;
        outp[(((size_t)(bb * H_ + h) * S_ + s) << 6) + hd] =
            f2bf(acc[mi][ni][r] + bias);
      }
    }
  }
}

// ---------------- out GEMM (M=8192, N=1024, K=1024), fp32 out --------------
// 512 blocks, same XCD map (64 row x 8 col tiles).
__global__ __launch_bounds__(256) void gemm_out_k(
    const unsigned short* __restrict__ A, const unsigned short* __restrict__ Bt,
    const float* __restrict__ bias, float* __restrict__ o_) {
  __shared__ unsigned short As[128 * 32];
  __shared__ unsigned short Bs[128 * 32];
  const int g = blockIdx.x;
  const int o = g & 7, gg = g >> 3;               // gg in 0..63
  const int row0 = (o * 8 + (gg & 7)) * 128;
  const int col0 = (gg >> 3) * 128;

  const int tid = threadIdx.x;
  const int lane = tid & 63;
  const int wid = tid >> 6;
  const int wm = wid >> 1, wn = wid & 1;

  f32x4 acc[4][4] = {};
  const int frow = lane & 15;
  const int koff = (lane >> 4) << 3;

  for (int kt = 0; kt < 32; ++kt) {
#pragma unroll
    for (int i = 0; i < 2; ++i) {
      int c = tid + (i << 8);
      int r = c >> 2;
      int kk = (c & 3) << 3;
      GLD16(A + (size_t)(row0 + r) * D_ + (kt << 5) + kk, (char*)As + c * 16);
      GLD16(Bt + (size_t)(col0 + r) * D_ + (kt << 5) + kk, (char*)Bs + c * 16);
    }
    __syncthreads();
    short8 af[4], bfr[4];
#pragma unroll
    for (int mi = 0; mi < 4; ++mi)
      af[mi] = *reinterpret_cast<const short8*>(
          &As[(wm * 64 + mi * 16 + frow) * 32 + koff]);
#pragma unroll
    for (int ni = 0; ni < 4; ++ni)
      bfr[ni] = *reinterpret_cast<const short8*>(
          &Bs[(wn * 64 + ni * 16 + frow) * 32 + koff]);
#pragma unroll
    for (int mi = 0; mi < 4; ++mi)
#pragma unroll
      for (int ni = 0; ni < 4; ++ni)
        acc[mi][ni] = MFMA16(af[mi], bfr[ni], acc[mi][ni]);
    __syncthreads();
  }

#pragma unroll
  for (int mi = 0; mi < 4; ++mi) {
#pragma unroll
    for (int ni = 0; ni < 4; ++ni) {
#pragma unroll
      for (int r = 0; r < 4; ++r) {
        int gr = row0 + wm * 64 + mi * 16 + ((lane >> 4) << 2) + r;
        int gc = col0 + wn * 64 + ni * 16 + (lane & 15);
        o_[(size_t)gr * D_ + gc] = acc[mi][ni][r] + bias[gc];
      }
    }
  }
}

// ---------------- banded attention + full weights-row write ----------------
// one wave per (b,h,q) row; 64 lanes write the entire 2048-float row
// (zeros + 9 band values) as 512 coalesced NT f32x4 stores.
__global__ __launch_bounds__(256) void attn_k(const unsigned short* __restrict__ Q,
                                              const unsigned short* __restrict__ K,
                                              const unsigned short* __restrict__ V,
                                              float* __restrict__ wout,
                                              unsigned short* __restrict__ attn) {
  int lane = threadIdx.x & 63;
  int wid = threadIdx.x >> 6;
  int row = blockIdx.x * 4 + wid;       // bh*2048 + s
  int s = row & (S_ - 1);
  int bh = row >> 11;                   // b*16 + h
  int b = bh >> 4, h = bh & 15;
  float qd = bf2f(Q[(size_t)row * HD_ + lane]);
  const unsigned short* Kb = K + (size_t)bh * S_ * HD_;
  const unsigned short* Vb = V + (size_t)bh * S_ * HD_;

  float sc[9];
#pragma unroll
  for (int j = 0; j < 9; ++j) {
    int ks = s - WIN_ + j;
    bool ok = (ks >= 0) && (ks < S_);
    float v = ok ? qd * bf2f(Kb[(size_t)ks * HD_ + lane]) : 0.f;
#pragma unroll
    for (int off = 32; off > 0; off >>= 1) v += __shfl_xor(v, off, 64);
    sc[j] = ok ? v * 0.125f : -INFINITY;  // 1/sqrt(64)
  }
  float m = sc[0];
#pragma unroll
  for (int j = 1; j < 9; ++j) m = fmaxf(m, sc[j]);
  float w[9];
  float sum = 0.f;
#pragma unroll
  for (int j = 0; j < 9; ++j) { w[j] = __expf(sc[j] - m); sum += w[j]; }
  float inv = 1.f / sum;
#pragma unroll
  for (int j = 0; j < 9; ++j) w[j] *= inv;  // wave-uniform normalized weights

  float o = 0.f;
#pragma unroll
  for (int j = 0; j < 9; ++j) {
    int ks = s - WIN_ + j;
    if (ks >= 0 && ks < S_) o += w[j] * bf2f(Vb[(size_t)ks * HD_ + lane]);
  }
  attn[((size_t)(b * S_ + s)) * D_ + h * HD_ + lane] = f2bf(o);

  // ---- full weights row: 8 NT f32x4 per lane, band select-merged ----
  f32x4* rowp = reinterpret_cast<f32x4*>(wout + (size_t)row * S_);
  const int lo = s - WIN_;              // first band col (may be <0)
  const int hi = s + WIN_;              // last band col (may be >=S_)
#pragma unroll
  for (int i = 0; i < 8; ++i) {
    int f = lane + (i << 6);            // f32x4 chunk 0..511
    int c0 = f << 2;                    // first col of chunk
    f32x4 v4 = {0.f, 0.f, 0.f, 0.f};
    if (c0 + 3 >= lo && c0 <= hi) {     // chunk overlaps band (<=3 lanes)
#pragma unroll
      for (int e = 0; e < 4; ++e) {
        int d = c0 + e - lo;            // band index if in [0,8]
        float val = 0.f;
#pragma unroll
        for (int j = 0; j < 9; ++j)
          if (d == j) val = w[j];       // static-index select chain
        v4[e] = val;
      }
    }
    __builtin_nontemporal_store(v4, rowp + f);
  }
}

// ---------------------------------------------------------------------------
extern "C" void kernel_launch(void* const* d_in, const int* in_sizes, int n_in,
                              void* d_out, int out_size, void* d_ws,
                              size_t ws_size, hipStream_t stream) {
  const float* x = (const float*)d_in[0];
  const float* Wq = (const float*)d_in[1];
  const float* bq = (const float*)d_in[2];
  const float* Wk = (const float*)d_in[3];
  const float* bk = (const float*)d_in[4];
  const float* Wv = (const float*)d_in[5];
  const float* bv = (const float*)d_in[6];
  const float* Wo = (const float*)d_in[7];
  const float* bo = (const float*)d_in[8];
  float* out = (float*)d_out;
  float* wout = out + OUT0_ELEMS;

  char* ws = (char*)d_ws;
  unsigned short* x_bf = (unsigned short*)(ws);                  // 16 MB @ 0
  unsigned short* Wt = (unsigned short*)(ws + (16ull << 20));    //  8 MB @ 16
  unsigned short* Qb = (unsigned short*)(ws + (24ull << 20));    // 16 MB @ 24
  unsigned short* Kb = (unsigned short*)(ws + (40ull << 20));    // 16 MB @ 40
  unsigned short* Vb = (unsigned short*)(ws + (56ull << 20));    // 16 MB @ 56
  unsigned short* attn = (unsigned short*)(ws + (72ull << 20));  // 16 MB @ 72

  prep_k<<<12288, 256, 0, stream>>>(x, Wq, Wk, Wv, Wo, x_bf, Wt);
  gemm_qkv_k<<<1536, 256, 0, stream>>>(x_bf, Wt, bq, bk, bv, Qb, Kb, Vb);
  attn_k<<<(B_ * H_ * S_) / 4, 256, 0, stream>>>(Qb, Kb, Vb, wout, attn);
  gemm_out_k<<<512, 256, 0, stream>>>(attn, Wt + (size_t)3 * D_ * D_, bo, out);
}